// Round 9
// baseline (1393.543 us; speedup 1.0000x reference)
//
#include <hip/hip_runtime.h>

#define Bn 64
#define Sn 512
#define Hn 1024
#define Tn 67

#define LOG2E 1.4426950408889634f
#define LN2   0.6931471805599453f

// ---------------------------------------------------------------------------
// Kernel 1: em = leaky_relu(hidden, 0.01) @ W + b  (unchanged, frozen)
// ---------------------------------------------------------------------------
__global__ __launch_bounds__(256) void gemm_em(
    const float* __restrict__ hidden, const float* __restrict__ W,
    const float* __restrict__ bias, float* __restrict__ em,
    float* __restrict__ out)
{
    __shared__ __align__(16) float hs[64][36];
    __shared__ __align__(16) float wt[80][36];

    const int tid = threadIdx.x;
    const int tx = tid & 15, ty = tid >> 4;
    const int row0 = blockIdx.x * 64;

    if (blockIdx.x == 0 && tid == 0) out[0] = 0.0f;

    float acc[4][5];
#pragma unroll
    for (int u = 0; u < 4; ++u)
#pragma unroll
        for (int v = 0; v < 5; ++v) acc[u][v] = 0.f;

    for (int kc = 0; kc < Hn; kc += 32) {
#pragma unroll
        for (int l = 0; l < 2; ++l) {
            int idx = tid + l * 256;
            int r = idx >> 3, kq = (idx & 7) << 2;
            float4 v = *reinterpret_cast<const float4*>(
                &hidden[(size_t)(row0 + r) * Hn + kc + kq]);
            v.x = v.x > 0.f ? v.x : 0.01f * v.x;
            v.y = v.y > 0.f ? v.y : 0.01f * v.y;
            v.z = v.z > 0.f ? v.z : 0.01f * v.z;
            v.w = v.w > 0.f ? v.w : 0.01f * v.w;
            *reinterpret_cast<float4*>(&hs[r][kq]) = v;
        }
        for (int idx = tid; idx < 32 * Tn; idx += 256) {
            int k = idx / Tn;
            int t = idx - k * Tn;
            wt[t][k] = W[(size_t)(kc + k) * Tn + t];
        }
        __syncthreads();

#pragma unroll
        for (int k0 = 0; k0 < 32; k0 += 4) {
            float4 hv[4], wv[5];
#pragma unroll
            for (int u = 0; u < 4; ++u)
                hv[u] = *reinterpret_cast<float4*>(&hs[ty + 16 * u][k0]);
#pragma unroll
            for (int v = 0; v < 5; ++v)
                wv[v] = *reinterpret_cast<float4*>(&wt[tx + 16 * v][k0]);
#pragma unroll
            for (int u = 0; u < 4; ++u)
#pragma unroll
                for (int v = 0; v < 5; ++v) {
                    acc[u][v] = fmaf(hv[u].x, wv[v].x, acc[u][v]);
                    acc[u][v] = fmaf(hv[u].y, wv[v].y, acc[u][v]);
                    acc[u][v] = fmaf(hv[u].z, wv[v].z, acc[u][v]);
                    acc[u][v] = fmaf(hv[u].w, wv[v].w, acc[u][v]);
                }
        }
        __syncthreads();
    }

#pragma unroll
    for (int v = 0; v < 5; ++v) {
        int c = tx + 16 * v;
        if (c < Tn) {
            float bb = bias[c];
#pragma unroll
            for (int u = 0; u < 4; ++u) {
                int row = row0 + ty + 16 * u;
                em[(size_t)row * Tn + c] = acc[u][v] + bb;
            }
        }
    }
}

// ---------------------------------------------------------------------------
// Kernel 2: barrier-free per-batch scans. 64 blocks x 192 threads (3 waves).
// r6 structure, but transition tables live in LDS float4-column layout
// (tbl[q*68 + j] = sources 4q..4q+3 for target j): per-lane consecutive
// float4 reads -> conflict-free ds_read_b128, ~12cy, replacing scratch.
// wave0 = CRF (extras 64-66 via reg contributions + shfl_xor SUM butterfly)
// wave1 = Viterbi (extras via r6's exact u64-key MAX butterfly; tags exact)
// wave2 = numerator.  One __syncthreads per wave at the end.
// ---------------------------------------------------------------------------
__device__ __forceinline__ unsigned long long shflx64(unsigned long long v, int m) {
    unsigned int lo = (unsigned int)v, hi = (unsigned int)(v >> 32);
    lo = __shfl_xor(lo, m);
    hi = __shfl_xor(hi, m);
    return ((unsigned long long)hi << 32) | lo;
}

__device__ __forceinline__ unsigned long long packkey(float v, int idx) {
    unsigned int b = __float_as_uint(v);
    unsigned int s = b ^ (unsigned int)(((int)b >> 31) | 0x80000000);
    return ((unsigned long long)s << 32) | (unsigned int)(127 - idx);
}

__device__ __forceinline__ float unpackval(unsigned long long key) {
    unsigned int s = (unsigned int)(key >> 32);
    unsigned int b = s ^ (unsigned int)((~(int)s >> 31) | 0x80000000);
    return __uint_as_float(b);
}

__global__ __launch_bounds__(192, 1) void crf_scan6(
    const float* __restrict__ em, const int* __restrict__ labels,
    const int* __restrict__ mask, const float* __restrict__ startT,
    const float* __restrict__ endT, const float* __restrict__ trans,
    float* __restrict__ out)
{
    __shared__ __align__(16) float emC[2][1088];   // 16 rows x 68, CRF wave
    __shared__ __align__(16) float emV[2][1088];   // Viterbi wave
    __shared__ int maskC[Sn];
    __shared__ int maskV[Sn];
    __shared__ __align__(16) float pb[2][72];
    __shared__ __align__(16) float vb[2][72];
    __shared__ __align__(16) float4 EcT[17 * 68];  // exp(trans) col-major f4
    __shared__ __align__(16) float4 TcT[17 * 68];  // trans col-major f4
    __shared__ unsigned char hist[Sn - 1][68];
    __shared__ int tg[Sn];
    __shared__ float numSh;
    __shared__ int lenSh;

    const int tid = threadIdx.x;
    const int wid = tid >> 6;
    const int lane = tid & 63;
    const int b = blockIdx.x;
    const float* emg = em + (size_t)b * Sn * Tn;
    const int u2 = lane < 3 ? lane : 2;
    const int st2 = 64 + u2;

    if (wid == 0) {
        // ================= CRF wave =================
#pragma unroll
        for (int i = 0; i < 8; ++i)
            maskC[lane + i * 64] = mask[b * Sn + lane + i * 64];

        // build exp(trans) table, column-major float4 over sources
        for (int idx = lane; idx < 17 * 68; idx += 64) {
            int i4 = idx / 68, j = idx - i4 * 68;
            float4 e;
            int i0 = 4 * i4;
            e.x = (i0 + 0 < Tn && j < Tn) ? exp2f(trans[(i0 + 0) * Tn + j] * LOG2E) : 0.f;
            e.y = (i0 + 1 < Tn && j < Tn) ? exp2f(trans[(i0 + 1) * Tn + j] * LOG2E) : 0.f;
            e.z = (i0 + 2 < Tn && j < Tn) ? exp2f(trans[(i0 + 2) * Tn + j] * LOG2E) : 0.f;
            e.w = (i0 + 3 < Tn && j < Tn) ? exp2f(trans[(i0 + 3) * Tn + j] * LOG2E) : 0.f;
            EcT[idx] = e;
        }
        float Esf[3], Ess[3];
#pragma unroll
        for (int u = 0; u < 3; ++u) {
            Esf[u] = exp2f(trans[lane * Tn + 64 + u] * LOG2E);
            Ess[u] = exp2f(trans[st2 * Tn + 64 + u] * LOG2E);
        }

        float sreg[17];
#pragma unroll
        for (int i = 0; i < 17; ++i) { int idx = lane + i * 64; if (idx > 1071) idx = 1071; sreg[i] = emg[idx]; }
#pragma unroll
        for (int i = 0; i < 17; ++i) {
            int idx = lane + i * 64;
            if (idx < 1072) { int s = idx / 67; emC[0][s * 68 + (idx - s * 67)] = sreg[i]; }
        }
#pragma unroll
        for (int i = 0; i < 17; ++i) { int idx = lane + i * 64; if (idx > 1071) idx = 1071; sreg[i] = emg[1072 + idx]; }

        if (lane == 0) { pb[0][67] = 0.f; pb[1][67] = 0.f; }

        float sc1 = startT[lane] + emC[0][lane];
        float sc2 = startT[st2] + emC[0][st2];
        float M = __shfl(sc1, 0);
        float p1 = exp2f((sc1 - M) * LOG2E);
        float p2 = exp2f((sc2 - M) * LOG2E);
        pb[0][lane] = p1;
        if (lane < 3) pb[0][64 + lane] = p2;
        float Mprev = M;

        for (int t = 1; t < Sn; ++t) {
            const int cb = (t >> 4) & 1;
            if ((t & 15) == 0) {
                const int k = t >> 4;
#pragma unroll
                for (int i = 0; i < 17; ++i) {
                    int idx = lane + i * 64;
                    if (idx < 1072) { int s = idx / 67; emC[cb][s * 68 + (idx - s * 67)] = sreg[i]; }
                }
                if (k < 31) {
                    const float* src = emg + (size_t)(k + 1) * 1072;
#pragma unroll
                    for (int i = 0; i < 17; ++i) { int idx = lane + i * 64; if (idx > 1071) idx = 1071; sreg[i] = src[idx]; }
                }
            }
            const float* row = &emC[cb][(t & 15) * 68];
            float em1 = row[lane];
            float em2 = row[st2];
            int m = maskC[t];

            const float4* P = (const float4*)&pb[(t + 1) & 1][0];
            float a0 = 0, a1 = 0, a2 = 0, a3 = 0;
#pragma unroll
            for (int q = 0; q < 17; ++q) {
                float4 pv = P[q];
                float4 e = EcT[q * 68 + lane];
                a0 = fmaf(pv.x, e.x, a0);
                a1 = fmaf(pv.y, e.y, a1);
                a2 = fmaf(pv.z, e.z, a2);
                a3 = fmaf(pv.w, e.w, a3);
            }
            float s1 = (a0 + a1) + (a2 + a3);

            // contributions to targets 64..66 (sum over sources via butterfly)
            float g0 = p1 * Esf[0], g1 = p1 * Esf[1], g2 = p1 * Esf[2];
            if (lane < 3) {
                g0 = fmaf(p2, Ess[0], g0);
                g1 = fmaf(p2, Ess[1], g1);
                g2 = fmaf(p2, Ess[2], g2);
            }
#pragma unroll
            for (int k = 1; k < 64; k <<= 1) {
                g0 += __shfl_xor(g0, k);
                g1 += __shfl_xor(g1, k);
                g2 += __shfl_xor(g2, k);
            }
            float s2 = (u2 == 0) ? g0 : (u2 == 1) ? g1 : g2;

            float n1 = Mprev + log2f(s1) * LN2 + em1;
            float n2 = Mprev + log2f(s2) * LN2 + em2;
            if (m) { sc1 = n1; sc2 = n2; }
            M = __shfl(sc1, 0);
            p1 = exp2f((sc1 - M) * LOG2E);
            p2 = exp2f((sc2 - M) * LOG2E);
            float* Wp = &pb[t & 1][0];
            Wp[lane] = p1;
            if (lane < 3) Wp[64 + lane] = p2;
            Mprev = M;
        }

        // denominator (wave-wide redundant reduce)
        float* F = &pb[0][0];
        F[lane] = sc1 + endT[lane];
        if (lane < 3) F[64 + lane] = sc2 + endT[64 + lane];
        if (lane == 0) F[67] = -1e30f;
        float mx = -1e30f;
        const float4* Fv = (const float4*)F;
#pragma unroll
        for (int q = 0; q < 17; ++q) {
            float4 v = Fv[q];
            mx = fmaxf(mx, fmaxf(fmaxf(v.x, v.y), fmaxf(v.z, v.w)));
        }
        float ss = 0.f;
#pragma unroll
        for (int q = 0; q < 17; ++q) {
            float4 v = Fv[q];
            ss += exp2f((v.x - mx) * LOG2E) + exp2f((v.y - mx) * LOG2E)
                + exp2f((v.z - mx) * LOG2E) + exp2f((v.w - mx) * LOG2E);
        }
        float denom = mx + log2f(ss) * LN2;
        __syncthreads();
        if (lane == 0) {
            int len = lenSh;
            float num = numSh + endT[labels[b * Sn + len - 1]];
            atomicAdd(out, -(num - denom) * (1.0f / (float)Bn));
        }
    } else if (wid == 1) {
        // ================= Viterbi wave =================
#pragma unroll
        for (int i = 0; i < 8; ++i)
            maskV[lane + i * 64] = mask[b * Sn + lane + i * 64];

        // build trans table, column-major float4 over sources
        for (int idx = lane; idx < 17 * 68; idx += 64) {
            int i4 = idx / 68, j = idx - i4 * 68;
            float4 e;
            int i0 = 4 * i4;
            e.x = (i0 + 0 < Tn && j < Tn) ? trans[(i0 + 0) * Tn + j] : 0.f;
            e.y = (i0 + 1 < Tn && j < Tn) ? trans[(i0 + 1) * Tn + j] : 0.f;
            e.z = (i0 + 2 < Tn && j < Tn) ? trans[(i0 + 2) * Tn + j] : 0.f;
            e.w = (i0 + 3 < Tn && j < Tn) ? trans[(i0 + 3) * Tn + j] : 0.f;
            TcT[idx] = e;
        }
        float Tsf[3], Tss[3];
        const int rsec = (lane < 3) ? (64 + lane) : 0;
#pragma unroll
        for (int u = 0; u < 3; ++u) {
            Tsf[u] = trans[lane * Tn + 64 + u];
            Tss[u] = trans[rsec * Tn + 64 + u];
        }

        float sreg[17];
#pragma unroll
        for (int i = 0; i < 17; ++i) { int idx = lane + i * 64; if (idx > 1071) idx = 1071; sreg[i] = emg[idx]; }
#pragma unroll
        for (int i = 0; i < 17; ++i) {
            int idx = lane + i * 64;
            if (idx < 1072) { int s = idx / 67; emV[0][s * 68 + (idx - s * 67)] = sreg[i]; }
        }
#pragma unroll
        for (int i = 0; i < 17; ++i) { int idx = lane + i * 64; if (idx > 1071) idx = 1071; sreg[i] = emg[1072 + idx]; }

        float sc1 = startT[lane] + emV[0][lane];
        float sc2 = startT[st2] + emV[0][st2];
        vb[0][lane] = sc1;
        if (lane < 3) vb[0][64 + lane] = sc2;
        if (lane == 0) { vb[0][67] = -1e30f; vb[1][67] = -1e30f; }

        for (int t = 1; t < Sn; ++t) {
            const int cb = (t >> 4) & 1;
            if ((t & 15) == 0) {
                const int k = t >> 4;
#pragma unroll
                for (int i = 0; i < 17; ++i) {
                    int idx = lane + i * 64;
                    if (idx < 1072) { int s = idx / 67; emV[cb][s * 68 + (idx - s * 67)] = sreg[i]; }
                }
                if (k < 31) {
                    const float* src = emg + (size_t)(k + 1) * 1072;
#pragma unroll
                    for (int i = 0; i < 17; ++i) { int idx = lane + i * 64; if (idx > 1071) idx = 1071; sreg[i] = src[idx]; }
                }
            }
            const float* row = &emV[cb][(t & 15) * 68];
            float em1 = row[lane];
            float e64 = row[64], e65 = row[65], e66 = row[66];
            int m = maskV[t];

            // ---- primary target tournament over 68 sources (T from LDS) ----
            const float4* Vp = (const float4*)&vb[(t + 1) & 1][0];
            float bv[17]; int bi[17];
#pragma unroll
            for (int q = 0; q < 17; ++q) {
                float4 v = Vp[q];
                float4 tt = TcT[q * 68 + lane];
                float c0 = v.x + tt.x;
                float c1 = v.y + tt.y;
                float c2 = v.z + tt.z;
                float c3 = v.w + tt.w;
                bool r0 = c1 > c0;
                float m01v = r0 ? c1 : c0; int m01i = r0 ? 4 * q + 1 : 4 * q + 0;
                bool r1 = c3 > c2;
                float m23v = r1 ? c3 : c2; int m23i = r1 ? 4 * q + 3 : 4 * q + 2;
                bool r2 = m23v > m01v;
                bv[q] = r2 ? m23v : m01v; bi[q] = r2 ? m23i : m01i;
            }
#pragma unroll
            for (int q = 0; q < 8; ++q) {
                bool r = bv[2 * q + 1] > bv[2 * q];
                bv[q] = r ? bv[2 * q + 1] : bv[2 * q];
                bi[q] = r ? bi[2 * q + 1] : bi[2 * q];
            }
            bv[8] = bv[16]; bi[8] = bi[16];
#pragma unroll
            for (int q = 0; q < 4; ++q) {
                bool r = bv[2 * q + 1] > bv[2 * q];
                bv[q] = r ? bv[2 * q + 1] : bv[2 * q];
                bi[q] = r ? bi[2 * q + 1] : bi[2 * q];
            }
            bv[4] = bv[8]; bi[4] = bi[8];
#pragma unroll
            for (int q = 0; q < 2; ++q) {
                bool r = bv[2 * q + 1] > bv[2 * q];
                bv[q] = r ? bv[2 * q + 1] : bv[2 * q];
                bi[q] = r ? bi[2 * q + 1] : bi[2 * q];
            }
            bv[2] = bv[4]; bi[2] = bi[4];
            { bool r = bv[1] > bv[0]; bv[0] = r ? bv[1] : bv[0]; bi[0] = r ? bi[1] : bi[0]; }
            { bool r = bv[2] > bv[0]; bv[0] = r ? bv[2] : bv[0]; bi[0] = r ? bi[2] : bi[0]; }
            float n1 = bv[0] + em1;

            // ---- targets 64..66 via u64-key shuffle reduce (exact ties) ----
            float ca = sc1 + Tsf[0]; int ia = lane;
            float cbv = sc1 + Tsf[1]; int ib = lane;
            float cc = sc1 + Tsf[2]; int ic = lane;
            if (lane < 3) {
                float sa = sc2 + Tss[0]; if (sa > ca)  { ca = sa;  ia = 64 + lane; }
                float sb = sc2 + Tss[1]; if (sb > cbv) { cbv = sb; ib = 64 + lane; }
                float scv = sc2 + Tss[2]; if (scv > cc) { cc = scv; ic = 64 + lane; }
            }
            unsigned long long k0 = packkey(ca, ia);
            unsigned long long k1 = packkey(cbv, ib);
            unsigned long long k2 = packkey(cc, ic);
#pragma unroll
            for (int k = 1; k < 64; k <<= 1) {
                unsigned long long o0 = shflx64(k0, k); if (o0 > k0) k0 = o0;
                unsigned long long o1 = shflx64(k1, k); if (o1 > k1) k1 = o1;
                unsigned long long o2 = shflx64(k2, k); if (o2 > k2) k2 = o2;
            }
            float v64 = unpackval(k0) + e64;
            float v65 = unpackval(k1) + e65;
            float v66 = unpackval(k2) + e66;
            int i64 = 127 - (int)(unsigned int)(k0 & 0xffffffffu);
            int i65 = 127 - (int)(unsigned int)(k1 & 0xffffffffu);
            int i66 = 127 - (int)(unsigned int)(k2 & 0xffffffffu);

            float nuv = (lane == 0) ? v64 : (lane == 1) ? v65 : v66;
            int nui = (lane == 0) ? i64 : (lane == 1) ? i65 : i66;

            int idx1 = m ? bi[0] : lane;
            int idx2 = m ? nui : st2;
            if (m) { sc1 = n1; sc2 = nuv; }

            hist[t - 1][lane] = (unsigned char)idx1;
            float* Wv = &vb[t & 1][0];
            Wv[lane] = sc1;
            if (lane < 3) {
                hist[t - 1][64 + lane] = (unsigned char)idx2;
                Wv[64 + lane] = sc2;
            }
        }

        // ---- final argmax (first index) over score + endT ----
        float* F = &vb[0][0];
        F[lane] = sc1 + endT[lane];
        if (lane < 3) F[64 + lane] = sc2 + endT[64 + lane];
        if (lane == 0) F[67] = -1e30f;
        const float4* Fv = (const float4*)F;
        float bv[17]; int bi[17];
#pragma unroll
        for (int q = 0; q < 17; ++q) {
            float4 v = Fv[q];
            bool r0 = v.y > v.x;
            float m01v = r0 ? v.y : v.x; int m01i = r0 ? 4 * q + 1 : 4 * q + 0;
            bool r1 = v.w > v.z;
            float m23v = r1 ? v.w : v.z; int m23i = r1 ? 4 * q + 3 : 4 * q + 2;
            bool r2 = m23v > m01v;
            bv[q] = r2 ? m23v : m01v; bi[q] = r2 ? m23i : m01i;
        }
#pragma unroll
        for (int q = 0; q < 8; ++q) {
            bool r = bv[2 * q + 1] > bv[2 * q];
            bv[q] = r ? bv[2 * q + 1] : bv[2 * q];
            bi[q] = r ? bi[2 * q + 1] : bi[2 * q];
        }
        bv[8] = bv[16]; bi[8] = bi[16];
#pragma unroll
        for (int q = 0; q < 4; ++q) {
            bool r = bv[2 * q + 1] > bv[2 * q];
            bv[q] = r ? bv[2 * q + 1] : bv[2 * q];
            bi[q] = r ? bi[2 * q + 1] : bi[2 * q];
        }
        bv[4] = bv[8]; bi[4] = bi[8];
#pragma unroll
        for (int q = 0; q < 2; ++q) {
            bool r = bv[2 * q + 1] > bv[2 * q];
            bv[q] = r ? bv[2 * q + 1] : bv[2 * q];
            bi[q] = r ? bi[2 * q + 1] : bi[2 * q];
        }
        bv[2] = bv[4]; bi[2] = bi[4];
        { bool r = bv[1] > bv[0]; bv[0] = r ? bv[1] : bv[0]; bi[0] = r ? bi[1] : bi[0]; }
        { bool r = bv[2] > bv[0]; bv[0] = r ? bv[2] : bv[0]; bi[0] = r ? bi[2] : bi[0]; }

        if (lane == 0) {
            int carry = bi[0];
            tg[Sn - 1] = carry;
            for (int k = Sn - 2; k >= 0; --k) {
                carry = hist[k][carry];
                tg[k] = carry;
            }
        }
        float* tagsOut = out + 1 + b * Sn;
#pragma unroll
        for (int i = 0; i < 8; ++i) {
            int s = lane + i * 64;
            tagsOut[s] = maskV[s] ? (float)tg[s] : 0.f;
        }
        __syncthreads();
    } else {
        // ================= numerator wave =================
        float part = 0.f; int lenp = 0;
#pragma unroll
        for (int i = 0; i < 8; ++i) {
            int s = lane + i * 64;
            int ms = mask[b * Sn + s];
            lenp += ms;
            int ls = labels[b * Sn + s];
            if (s == 0) {
                part += startT[ls] + emg[ls];
            } else if (ms) {
                int lp = labels[b * Sn + s - 1];
                part += trans[lp * Tn + ls] + emg[(size_t)s * Tn + ls];
            }
        }
#pragma unroll
        for (int k = 1; k < 64; k <<= 1) {
            part += __shfl_xor(part, k);
            lenp += __shfl_xor(lenp, k);
        }
        if (lane == 0) { numSh = part; lenSh = lenp; }
        __syncthreads();
    }
}

extern "C" void kernel_launch(void* const* d_in, const int* in_sizes, int n_in,
                              void* d_out, int out_size, void* d_ws, size_t ws_size,
                              hipStream_t stream) {
    const float* hidden = (const float*)d_in[0];
    const int*   labels = (const int*)d_in[1];
    const int*   maskp  = (const int*)d_in[2];
    const float* W      = (const float*)d_in[3];
    const float* bias   = (const float*)d_in[4];
    const float* startT = (const float*)d_in[5];
    const float* endT   = (const float*)d_in[6];
    const float* trans  = (const float*)d_in[7];
    float* out = (float*)d_out;
    float* em  = out + 1 + (size_t)Bn * Sn;

    hipLaunchKernelGGL(gemm_em, dim3((Bn * Sn) / 64), dim3(256), 0, stream,
                       hidden, W, bias, em, out);
    hipLaunchKernelGGL(crf_scan6, dim3(Bn), dim3(192), 0, stream,
                       em, labels, maskp, startT, endT, trans, out);
}

// Round 10
// 893.062 us; speedup vs baseline: 1.5604x; 1.5604x over previous
//
#include <hip/hip_runtime.h>

#define Bn 64
#define Sn 512
#define Hn 1024
#define Tn 67

#define LOG2E 1.4426950408889634f
#define LN2   0.6931471805599453f

// ---------------------------------------------------------------------------
// Kernel 1: em = leaky_relu(hidden, 0.01) @ W + b  (unchanged, frozen)
// ---------------------------------------------------------------------------
__global__ __launch_bounds__(256) void gemm_em(
    const float* __restrict__ hidden, const float* __restrict__ W,
    const float* __restrict__ bias, float* __restrict__ em,
    float* __restrict__ out)
{
    __shared__ __align__(16) float hs[64][36];
    __shared__ __align__(16) float wt[80][36];

    const int tid = threadIdx.x;
    const int tx = tid & 15, ty = tid >> 4;
    const int row0 = blockIdx.x * 64;

    if (blockIdx.x == 0 && tid == 0) out[0] = 0.0f;

    float acc[4][5];
#pragma unroll
    for (int u = 0; u < 4; ++u)
#pragma unroll
        for (int v = 0; v < 5; ++v) acc[u][v] = 0.f;

    for (int kc = 0; kc < Hn; kc += 32) {
#pragma unroll
        for (int l = 0; l < 2; ++l) {
            int idx = tid + l * 256;
            int r = idx >> 3, kq = (idx & 7) << 2;
            float4 v = *reinterpret_cast<const float4*>(
                &hidden[(size_t)(row0 + r) * Hn + kc + kq]);
            v.x = v.x > 0.f ? v.x : 0.01f * v.x;
            v.y = v.y > 0.f ? v.y : 0.01f * v.y;
            v.z = v.z > 0.f ? v.z : 0.01f * v.z;
            v.w = v.w > 0.f ? v.w : 0.01f * v.w;
            *reinterpret_cast<float4*>(&hs[r][kq]) = v;
        }
        for (int idx = tid; idx < 32 * Tn; idx += 256) {
            int k = idx / Tn;
            int t = idx - k * Tn;
            wt[t][k] = W[(size_t)(kc + k) * Tn + t];
        }
        __syncthreads();

#pragma unroll
        for (int k0 = 0; k0 < 32; k0 += 4) {
            float4 hv[4], wv[5];
#pragma unroll
            for (int u = 0; u < 4; ++u)
                hv[u] = *reinterpret_cast<float4*>(&hs[ty + 16 * u][k0]);
#pragma unroll
            for (int v = 0; v < 5; ++v)
                wv[v] = *reinterpret_cast<float4*>(&wt[tx + 16 * v][k0]);
#pragma unroll
            for (int u = 0; u < 4; ++u)
#pragma unroll
                for (int v = 0; v < 5; ++v) {
                    acc[u][v] = fmaf(hv[u].x, wv[v].x, acc[u][v]);
                    acc[u][v] = fmaf(hv[u].y, wv[v].y, acc[u][v]);
                    acc[u][v] = fmaf(hv[u].z, wv[v].z, acc[u][v]);
                    acc[u][v] = fmaf(hv[u].w, wv[v].w, acc[u][v]);
                }
        }
        __syncthreads();
    }

#pragma unroll
    for (int v = 0; v < 5; ++v) {
        int c = tx + 16 * v;
        if (c < Tn) {
            float bb = bias[c];
#pragma unroll
            for (int u = 0; u < 4; ++u) {
                int row = row0 + ty + 16 * u;
                em[(size_t)row * Tn + c] = acc[u][v] + bb;
            }
        }
    }
}

// ---------------------------------------------------------------------------
// Kernel 2: barrier-free scans, FULLY SCALARIZED inner loops (no indexed
// locals anywhere in the steady state -> nothing can spill to scratch).
// 64 blocks x 192 threads (3 waves):
//   wave0 = CRF     (tables in LDS, dual-column, 1 shfl/step)
//   wave1 = Viterbi (named-f4 candidates, fmax tree + equality-min argmax,
//                    extras via f32 butterfly + ballot/ffs first-index)
//   wave2 = numerator
// em: per-step coalesced L2 column load, prefetched 1 step ahead (no staging).
// ---------------------------------------------------------------------------
#define R17(X) X(0) X(1) X(2) X(3) X(4) X(5) X(6) X(7) X(8) X(9) X(10) X(11) X(12) X(13) X(14) X(15) X(16)

__global__ __launch_bounds__(192, 1) void crf_scan7(
    const float* __restrict__ em, const int* __restrict__ labels,
    const int* __restrict__ mask, const float* __restrict__ startT,
    const float* __restrict__ endT, const float* __restrict__ trans,
    float* __restrict__ out)
{
    __shared__ __align__(16) float4 EcT4[17 * 68];  // exp(trans), col-major f4
    __shared__ __align__(16) float4 TcT4[17 * 68];  // trans, col-major f4
    __shared__ __align__(16) float pb[2][72];
    __shared__ __align__(16) float vb[2][72];
    __shared__ int maskC[Sn];
    __shared__ int maskV[Sn];
    __shared__ unsigned char hist[Sn - 1][68];
    __shared__ int tg[Sn];
    __shared__ float numSh;
    __shared__ int lenSh;

    const int tid = threadIdx.x;
    const int wid = tid >> 6;
    const int lane = tid & 63;
    const int b = blockIdx.x;
    const float* emg = em + (size_t)b * Sn * Tn;
    const int u2 = lane < 3 ? lane : 2;
    const int st2 = 64 + u2;

    if (wid == 0) {
        // ================= CRF wave =================
#pragma unroll
        for (int i = 0; i < 8; ++i)
            maskC[lane + i * 64] = mask[b * Sn + lane + i * 64];

        for (int idx = lane; idx < 17 * 68; idx += 64) {
            int i4 = idx / 68, j = idx - i4 * 68;
            int i0 = 4 * i4;
            float4 e;
            e.x = (i0 + 0 < Tn && j < Tn) ? exp2f(trans[(i0 + 0) * Tn + j] * LOG2E) : 0.f;
            e.y = (i0 + 1 < Tn && j < Tn) ? exp2f(trans[(i0 + 1) * Tn + j] * LOG2E) : 0.f;
            e.z = (i0 + 2 < Tn && j < Tn) ? exp2f(trans[(i0 + 2) * Tn + j] * LOG2E) : 0.f;
            e.w = (i0 + 3 < Tn && j < Tn) ? exp2f(trans[(i0 + 3) * Tn + j] * LOG2E) : 0.f;
            EcT4[idx] = e;
        }
        if (lane == 0) { pb[0][67] = 0.f; pb[1][67] = 0.f; }

        float em0a = emg[lane];
        float em0b = emg[st2];
        float sc1 = startT[lane] + em0a;
        float sc2 = startT[st2] + em0b;
        float M = __shfl(sc1, 0);
        float p1 = exp2f((sc1 - M) * LOG2E);
        float p2 = exp2f((sc2 - M) * LOG2E);
        pb[0][lane] = p1;
        if (lane < 3) pb[0][64 + lane] = p2;
        float Mprev = M;

        float emn1 = emg[Tn + lane];
        float emn2 = emg[Tn + st2];
        int mn = maskC[1];

        for (int t = 1; t < Sn; ++t) {
            float emc1 = emn1, emc2 = emn2;
            int m = mn;
            if (t + 1 < Sn) {
                emn1 = emg[(size_t)(t + 1) * Tn + lane];
                emn2 = emg[(size_t)(t + 1) * Tn + st2];
                mn = maskC[t + 1];
            }
            const float4* P = (const float4*)&pb[(t + 1) & 1][0];
            float a0 = 0, a1 = 0, a2 = 0, a3 = 0;
            float g0 = 0, g1 = 0, g2 = 0, g3 = 0;
#pragma unroll
            for (int q = 0; q < 17; ++q) {
                float4 pv = P[q];
                float4 e1 = EcT4[q * 68 + lane];
                float4 e2 = EcT4[q * 68 + 64 + u2];
                a0 = fmaf(pv.x, e1.x, a0); g0 = fmaf(pv.x, e2.x, g0);
                a1 = fmaf(pv.y, e1.y, a1); g1 = fmaf(pv.y, e2.y, g1);
                a2 = fmaf(pv.z, e1.z, a2); g2 = fmaf(pv.z, e2.z, g2);
                a3 = fmaf(pv.w, e1.w, a3); g3 = fmaf(pv.w, e2.w, g3);
            }
            float s1 = (a0 + a1) + (a2 + a3);
            float s2 = (g0 + g1) + (g2 + g3);
            float n1 = Mprev + log2f(s1) * LN2 + emc1;
            float n2 = Mprev + log2f(s2) * LN2 + emc2;
            if (m) { sc1 = n1; sc2 = n2; }
            M = __shfl(sc1, 0);
            p1 = exp2f((sc1 - M) * LOG2E);
            p2 = exp2f((sc2 - M) * LOG2E);
            float* Wp = &pb[t & 1][0];
            Wp[lane] = p1;
            if (lane < 3) Wp[64 + lane] = p2;
            Mprev = M;
        }

        // denominator
        float* F = &pb[0][0];
        F[lane] = sc1 + endT[lane];
        if (lane < 3) F[64 + lane] = sc2 + endT[64 + lane];
        if (lane == 0) F[67] = -1e30f;
        float mx = -1e30f;
        const float4* Fv = (const float4*)F;
#pragma unroll
        for (int q = 0; q < 17; ++q) {
            float4 v = Fv[q];
            mx = fmaxf(mx, fmaxf(fmaxf(v.x, v.y), fmaxf(v.z, v.w)));
        }
        float ss = 0.f;
#pragma unroll
        for (int q = 0; q < 17; ++q) {
            float4 v = Fv[q];
            ss += exp2f((v.x - mx) * LOG2E) + exp2f((v.y - mx) * LOG2E)
                + exp2f((v.z - mx) * LOG2E) + exp2f((v.w - mx) * LOG2E);
        }
        float denom = mx + log2f(ss) * LN2;
        __syncthreads();
        if (lane == 0) {
            int len = lenSh;
            float num = numSh + endT[labels[b * Sn + len - 1]];
            atomicAdd(out, -(num - denom) * (1.0f / (float)Bn));
        }
    } else if (wid == 1) {
        // ================= Viterbi wave =================
#pragma unroll
        for (int i = 0; i < 8; ++i)
            maskV[lane + i * 64] = mask[b * Sn + lane + i * 64];

        for (int idx = lane; idx < 17 * 68; idx += 64) {
            int i4 = idx / 68, j = idx - i4 * 68;
            int i0 = 4 * i4;
            float4 e;
            e.x = (i0 + 0 < Tn && j < Tn) ? trans[(i0 + 0) * Tn + j] : 0.f;
            e.y = (i0 + 1 < Tn && j < Tn) ? trans[(i0 + 1) * Tn + j] : 0.f;
            e.z = (i0 + 2 < Tn && j < Tn) ? trans[(i0 + 2) * Tn + j] : 0.f;
            e.w = (i0 + 3 < Tn && j < Tn) ? trans[(i0 + 3) * Tn + j] : 0.f;
            TcT4[idx] = e;
        }
        const int rsec = (lane < 3) ? (64 + lane) : 0;
        float Tsf0 = trans[lane * Tn + 64], Tsf1 = trans[lane * Tn + 65], Tsf2 = trans[lane * Tn + 66];
        float Tss0 = trans[rsec * Tn + 64], Tss1 = trans[rsec * Tn + 65], Tss2 = trans[rsec * Tn + 66];

        if (lane == 0) { vb[0][67] = -1e30f; vb[1][67] = -1e30f; }

        float em0a = emg[lane];
        float em0b = emg[st2];
        float sc1 = startT[lane] + em0a;
        float sc2 = startT[st2] + em0b;
        vb[0][lane] = sc1;
        if (lane < 3) vb[0][64 + lane] = sc2;

        float emn1 = emg[Tn + lane];
        float emn2 = emg[Tn + st2];
        int mn = maskV[1];

        for (int t = 1; t < Sn; ++t) {
            float emc1 = emn1, emc2 = emn2;
            int m = mn;
            if (t + 1 < Sn) {
                emn1 = emg[(size_t)(t + 1) * Tn + lane];
                emn2 = emg[(size_t)(t + 1) * Tn + st2];
                mn = maskV[t + 1];
            }
            const float4* Vbc = (const float4*)&vb[(t + 1) & 1][0];

            // ---- extras (targets 64..66): butterfly max + ballot first-index
            float x0 = sc1 + Tsf0, x1 = sc1 + Tsf1, x2 = sc1 + Tsf2;
            float y0 = sc2 + Tss0, y1 = sc2 + Tss1, y2 = sc2 + Tss2;
            float z0 = (lane < 3) ? fmaxf(x0, y0) : x0;
            float z1 = (lane < 3) ? fmaxf(x1, y1) : x1;
            float z2 = (lane < 3) ? fmaxf(x2, y2) : x2;
#pragma unroll
            for (int k = 1; k < 64; k <<= 1) {
                z0 = fmaxf(z0, __shfl_xor(z0, k));
                z1 = fmaxf(z1, __shfl_xor(z1, k));
                z2 = fmaxf(z2, __shfl_xor(z2, k));
            }
            unsigned long long ba0 = __ballot(x0 == z0);
            unsigned long long ba1 = __ballot(x1 == z1);
            unsigned long long ba2 = __ballot(x2 == z2);
            unsigned long long bb0 = __ballot((lane < 3) && (y0 == z0));
            unsigned long long bb1 = __ballot((lane < 3) && (y1 == z1));
            unsigned long long bb2 = __ballot((lane < 3) && (y2 == z2));
            int e0 = ba0 ? (__ffsll(ba0) - 1) : (64 + __ffsll(bb0) - 1);
            int e1 = ba1 ? (__ffsll(ba1) - 1) : (64 + __ffsll(bb1) - 1);
            int e2 = ba2 ? (__ffsll(ba2) - 1) : (64 + __ffsll(bb2) - 1);

            // ---- primary target: named-f4 candidates, no arrays ----
#define VDECL(i) float4 c##i; { float4 v = Vbc[i]; float4 tt = TcT4[i * 68 + lane]; \
            c##i.x = v.x + tt.x; c##i.y = v.y + tt.y; c##i.z = v.z + tt.z; c##i.w = v.w + tt.w; }
            R17(VDECL)
#undef VDECL
#define VQM(i) float mq##i = fmaxf(fmaxf(c##i.x, c##i.y), fmaxf(c##i.z, c##i.w));
            R17(VQM)
#undef VQM
            float m1 = fmaxf(
                fmaxf(fmaxf(fmaxf(mq0, mq1), fmaxf(mq2, mq3)),
                      fmaxf(fmaxf(mq4, mq5), fmaxf(mq6, mq7))),
                fmaxf(fmaxf(fmaxf(mq8, mq9), fmaxf(mq10, mq11)),
                      fmaxf(fmaxf(mq12, mq13), fmaxf(fmaxf(mq14, mq15), mq16))));
#define VIQ(i) int sel##i = (mq##i == m1) ? (4 * i + (c##i.x == mq##i ? 0 : (c##i.y == mq##i ? 1 : (c##i.z == mq##i ? 2 : 3)))) : 1023;
            R17(VIQ)
#undef VIQ
            int idxp = min(
                min(min(min(sel0, sel1), min(sel2, sel3)),
                    min(min(sel4, sel5), min(sel6, sel7))),
                min(min(min(sel8, sel9), min(sel10, sel11)),
                    min(min(sel12, sel13), min(min(sel14, sel15), sel16))));

            float n1 = m1 + emc1;
            float nuv = ((u2 == 0) ? z0 : (u2 == 1) ? z1 : z2) + emc2;
            int nui = (u2 == 0) ? e0 : (u2 == 1) ? e1 : e2;

            int idx1 = m ? idxp : lane;
            int idx2 = m ? nui : st2;
            if (m) { sc1 = n1; sc2 = nuv; }

            hist[t - 1][lane] = (unsigned char)idx1;
            float* Wv = &vb[t & 1][0];
            Wv[lane] = sc1;
            if (lane < 3) {
                hist[t - 1][64 + lane] = (unsigned char)idx2;
                Wv[64 + lane] = sc2;
            }
        }

        // ---- final argmax (first index) over score + endT ----
        float f1 = sc1 + endT[lane];
        float f2 = (lane < 3) ? (sc2 + endT[64 + lane]) : -1e30f;
        float zf = fmaxf(f1, f2);
#pragma unroll
        for (int k = 1; k < 64; k <<= 1) zf = fmaxf(zf, __shfl_xor(zf, k));
        unsigned long long bf1 = __ballot(f1 == zf);
        unsigned long long bf2 = __ballot((lane < 3) && (f2 == zf));
        int best = bf1 ? (__ffsll(bf1) - 1) : (64 + __ffsll(bf2) - 1);

        if (lane == 0) {
            int carry = best;
            tg[Sn - 1] = carry;
            for (int k = Sn - 2; k >= 0; --k) {
                carry = hist[k][carry];
                tg[k] = carry;
            }
        }
        float* tagsOut = out + 1 + b * Sn;
#pragma unroll
        for (int i = 0; i < 8; ++i) {
            int s = lane + i * 64;
            tagsOut[s] = maskV[s] ? (float)tg[s] : 0.f;
        }
        __syncthreads();
    } else {
        // ================= numerator wave =================
        float part = 0.f; int lenp = 0;
#pragma unroll
        for (int i = 0; i < 8; ++i) {
            int s = lane + i * 64;
            int ms = mask[b * Sn + s];
            lenp += ms;
            int ls = labels[b * Sn + s];
            if (s == 0) {
                part += startT[ls] + emg[ls];
            } else if (ms) {
                int lp = labels[b * Sn + s - 1];
                part += trans[lp * Tn + ls] + emg[(size_t)s * Tn + ls];
            }
        }
#pragma unroll
        for (int k = 1; k < 64; k <<= 1) {
            part += __shfl_xor(part, k);
            lenp += __shfl_xor(lenp, k);
        }
        if (lane == 0) { numSh = part; lenSh = lenp; }
        __syncthreads();
    }
}

extern "C" void kernel_launch(void* const* d_in, const int* in_sizes, int n_in,
                              void* d_out, int out_size, void* d_ws, size_t ws_size,
                              hipStream_t stream) {
    const float* hidden = (const float*)d_in[0];
    const int*   labels = (const int*)d_in[1];
    const int*   maskp  = (const int*)d_in[2];
    const float* W      = (const float*)d_in[3];
    const float* bias   = (const float*)d_in[4];
    const float* startT = (const float*)d_in[5];
    const float* endT   = (const float*)d_in[6];
    const float* trans  = (const float*)d_in[7];
    float* out = (float*)d_out;
    float* em  = out + 1 + (size_t)Bn * Sn;

    hipLaunchKernelGGL(gemm_em, dim3((Bn * Sn) / 64), dim3(256), 0, stream,
                       hidden, W, bias, em, out);
    hipLaunchKernelGGL(crf_scan7, dim3(Bn), dim3(192), 0, stream,
                       em, labels, maskp, startT, endT, trans, out);
}